// Round 8
// baseline (6250.719 us; speedup 1.0000x reference)
//
#include <hip/hip_runtime.h>
#include <math.h>

#define N 2048

typedef unsigned int uint;

// ws layout: [0] prep 2048*16 f32 (131072 B) | [131072] W 2048^2 f32 (16777216 B)
#define W_OFF 131072
#define DENSE_NEED (131072ull + 16777216ull)

// Per-box precompute: corners (4x2), center, cos/sin, half-extents, area, bounding radius.
__global__ __launch_bounds__(256) void prep_kernel(const float* __restrict__ boxes, float* __restrict__ prep) {
#pragma clang fp contract(off)
  int i = blockIdx.x * 256 + threadIdx.x;
  if (i >= N) return;
  float xc = boxes[i * 5 + 0], yc = boxes[i * 5 + 1];
  float w = boxes[i * 5 + 2], h = boxes[i * 5 + 3], th = boxes[i * 5 + 4];
  float t = th * 0.017453292519943295f;
  float c = (float)cos((double)t);
  float s = (float)sin((double)t);
  float w2 = w * 0.5f, h2 = h * 0.5f;
  float lx[4] = {-w2, w2, w2, -w2};
  float ly[4] = {-h2, -h2, h2, h2};
  float* P = prep + i * 16;
#pragma unroll
  for (int k = 0; k < 4; k++) {
    P[k * 2 + 0] = (xc + lx[k] * c) - ly[k] * s;
    P[k * 2 + 1] = (yc + lx[k] * s) + ly[k] * c;
  }
  P[8] = xc; P[9] = yc; P[10] = c; P[11] = s; P[12] = w2; P[13] = h2;
  P[14] = w * h;
  P[15] = sqrtf(w2 * w2 + h2 * h2);
}

// Rotated-rect intersection weight, mirroring the reference op-for-op in fp32.
__device__ float pair_weight(const float* __restrict__ Pi, const float* __restrict__ Pj) {
#pragma clang fp contract(off)
  float ax[4], ay[4], bx[4], by[4];
#pragma unroll
  for (int k = 0; k < 4; k++) {
    ax[k] = Pi[2 * k]; ay[k] = Pi[2 * k + 1];
    bx[k] = Pj[2 * k]; by[k] = Pj[2 * k + 1];
  }
  float ptsx[24], ptsy[24];
  bool msk[24];
#pragma unroll
  for (int e = 0; e < 4; e++) {
    float Ax = ax[e], Ay = ay[e];
    float BAx = ax[(e + 1) & 3] - Ax, BAy = ay[(e + 1) & 3] - Ay;
#pragma unroll
    for (int f = 0; f < 4; f++) {
      float Cx = bx[f], Cy = by[f];
      float DCx = bx[(f + 1) & 3] - Cx, DCy = by[(f + 1) & 3] - Cy;
      float CAx = Cx - Ax, CAy = Cy - Ay;
      float den = BAx * DCy - BAy * DCx;
      bool dok = fabsf(den) > 1e-12f;
      float dens = dok ? den : 1.0f;
      float t = (CAx * DCy - CAy * DCx) / dens;
      float u = (CAx * BAy - CAy * BAx) / dens;
      int id = e * 4 + f;
      ptsx[id] = Ax + t * BAx;
      ptsy[id] = Ay + t * BAy;
      msk[id] = dok && (t >= 0.0f) && (t <= 1.0f) && (u >= 0.0f) && (u <= 1.0f);
    }
  }
  float xcj = Pj[8], ycj = Pj[9], cj = Pj[10], sj = Pj[11], w2j = Pj[12], h2j = Pj[13];
  float xci = Pi[8], yci = Pi[9], ci = Pi[10], si = Pi[11], w2i = Pi[12], h2i = Pi[13];
#pragma unroll
  for (int k = 0; k < 4; k++) {
    float dx = ax[k] - xcj, dy = ay[k] - ycj;
    float xl = dx * cj + dy * sj;
    float yl = -dx * sj + dy * cj;
    ptsx[16 + k] = ax[k]; ptsy[16 + k] = ay[k];
    msk[16 + k] = (fabsf(xl) <= w2j + 1e-5f) && (fabsf(yl) <= h2j + 1e-5f);
  }
#pragma unroll
  for (int k = 0; k < 4; k++) {
    float dx = bx[k] - xci, dy = by[k] - yci;
    float xl = dx * ci + dy * si;
    float yl = -dx * si + dy * ci;
    ptsx[20 + k] = bx[k]; ptsy[20 + k] = by[k];
    msk[20 + k] = (fabsf(xl) <= w2i + 1e-5f) && (fabsf(yl) <= h2i + 1e-5f);
  }
  int cnt = 0;
  float sx = 0.f, sy = 0.f;
#pragma unroll
  for (int k = 0; k < 24; k++) {
    if (msk[k]) { cnt++; sx += ptsx[k]; sy += ptsy[k]; }
  }
  float fc = (float)(cnt > 1 ? cnt : 1);
  float ctx = sx / fc, cty = sy / fc;
  float ang[24], px[24], py[24];
#pragma unroll
  for (int k = 0; k < 24; k++) {
    float rx = ptsx[k] - ctx, ry = ptsy[k] - cty;
    px[k] = rx; py[k] = ry;
    ang[k] = msk[k] ? (float)atan2((double)ry, (double)rx) : 1.0e3f;
  }
  // stable insertion sort ascending by angle (== stable argsort for any tie pattern)
  for (int a = 1; a < 24; a++) {
    float ka = ang[a], kx = px[a], ky = py[a];
    int b = a - 1;
    while (b >= 0 && ang[b] > ka) {
      ang[b + 1] = ang[b]; px[b + 1] = px[b]; py[b + 1] = py[b];
      b--;
    }
    ang[b + 1] = ka; px[b + 1] = kx; py[b + 1] = ky;
  }
  float term[24];
#pragma unroll
  for (int x = 0; x < 24; x++) {
    int nx = (x + 1 < cnt) ? x + 1 : 0;
    float cr = px[x] * py[nx] - py[x] * px[nx];
    term[x] = (x < cnt) ? cr : 0.0f;
  }
  // numpy pairwise summation order for n=24
  float r[8];
#pragma unroll
  for (int j = 0; j < 8; j++) r[j] = (term[j] + term[j + 8]) + term[j + 16];
  float ssum = ((r[0] + r[1]) + (r[2] + r[3])) + ((r[4] + r[5]) + (r[6] + r[7]));
  float area = 0.5f * fabsf(ssum);
  float inter = (cnt >= 3) ? area : 0.0f;
  float iou = inter / ((Pi[14] + Pj[14] - inter) + 1e-9f);
  return (iou > 0.3f) ? (1.0f - iou) : 1.0f;  // METHOD=1 linear decay
}

// Full N^2 weight matrix; bounding-circle filter inline (disjoint circles => inter==0
// exactly => w==1, bit-exact vs reference).
__global__ __launch_bounds__(256) void inter_kernel(const float* __restrict__ prep,
                                                    float* __restrict__ W) {
#pragma clang fp contract(off)
  uint gid = blockIdx.x * 256u + threadIdx.x;
  uint i = gid >> 11, j = gid & 2047u;
  const float* Pi = prep + i * 16;
  const float* Pj = prep + j * 16;
  float dx = Pi[8] - Pj[8], dy = Pi[9] - Pj[9];
  float rr = Pi[15] + Pj[15] + 1.0f;
  float w = 1.0f;
  if (dx * dx + dy * dy <= rr * rr) w = pair_weight(Pi, Pj);
  W[(size_t)i * N + j] = w;
}

// Block-wide argmax with first-index tie-break (matches np.argmax).
__device__ inline void block_argmax(const float* sc, const unsigned char* sel,
                                    float* rv, int* ri, int tid, float& mv_out, int& mi_out) {
  const float NINF = -__builtin_inff();
  float v0 = sel[tid] ? NINF : sc[tid];
  float v1 = sel[tid + 1024] ? NINF : sc[tid + 1024];
  float bv; int bi;
  if (v0 >= v1) { bv = v0; bi = tid; } else { bv = v1; bi = tid + 1024; }
#pragma unroll
  for (int off = 32; off > 0; off >>= 1) {
    float ov = __shfl_down(bv, off);
    int oi = __shfl_down(bi, off);
    if (ov > bv || (ov == bv && oi < bi)) { bv = ov; bi = oi; }
  }
  if ((tid & 63) == 0) { rv[tid >> 6] = bv; ri[tid >> 6] = bi; }
  __syncthreads();
  float mv = rv[0]; int mi = ri[0];
#pragma unroll
  for (int k = 1; k < 16; k++) {
    float ov = rv[k]; int oi = ri[k];
    if (ov > mv || (ov == mv && oi < mi)) { mv = ov; mi = oi; }
  }
  mv_out = mv; mi_out = mi;
}

// Sequential soft-NMS scan (dense W). OUTPUT IS FLOAT32: out[0:2048]=order,
// out[2048:4096]=keep, out[4096:6144]=rec.
__global__ __launch_bounds__(1024) void scan_dense(const float* __restrict__ W,
                                                   const float* __restrict__ scores,
                                                   float* __restrict__ out) {
  __shared__ float sc[N];
  __shared__ unsigned char sel[N];
  __shared__ float rv[16];
  __shared__ int ri[16];
  int tid = threadIdx.x;
  sc[tid] = scores[tid];
  sc[tid + 1024] = scores[tid + 1024];
  sel[tid] = 0;
  sel[tid + 1024] = 0;
  __syncthreads();
  for (int t = 0; t < N; ++t) {
    float mv; int mi;
    block_argmax(sc, sel, rv, ri, tid, mv, mi);
    if (tid == 0) {
      out[t] = (float)mi;                        // order
      out[N + t] = (mv > 0.001f) ? 1.0f : 0.0f;  // keep
      out[2 * N + t] = mv;                       // rec
    }
    if (tid == (mi & 1023)) sel[mi] = 1;  // slot owner == sole reader: race-free
    if (mv > 0.001f) {
      const float* Wr = W + (size_t)mi * N;
      float w0 = Wr[tid], w1 = Wr[tid + 1024];
      if (!sel[tid]) sc[tid] *= w0;
      if (!sel[tid + 1024]) sc[tid + 1024] *= w1;
    }
    __syncthreads();
  }
}

// Fallback (workspace too small for dense W): recompute selected row on the fly.
__global__ __launch_bounds__(1024) void scan_fly(const float* __restrict__ prep,
                                                 const float* __restrict__ scores,
                                                 float* __restrict__ out) {
  __shared__ float sc[N];
  __shared__ unsigned char sel[N];
  __shared__ float rv[16];
  __shared__ int ri[16];
  int tid = threadIdx.x;
  sc[tid] = scores[tid];
  sc[tid + 1024] = scores[tid + 1024];
  sel[tid] = 0;
  sel[tid + 1024] = 0;
  __syncthreads();
  for (int t = 0; t < N; ++t) {
    float mv; int mi;
    block_argmax(sc, sel, rv, ri, tid, mv, mi);
    if (tid == 0) {
      out[t] = (float)mi;
      out[N + t] = (mv > 0.001f) ? 1.0f : 0.0f;
      out[2 * N + t] = mv;
    }
    if (tid == (mi & 1023)) sel[mi] = 1;
    if (mv > 0.001f) {
      const float* Pm = prep + mi * 16;
#pragma unroll
      for (int half = 0; half < 2; half++) {
        int j = tid + half * 1024;
        if (!sel[j]) {
          const float* Pj = prep + j * 16;
          float dx = Pm[8] - Pj[8], dy = Pm[9] - Pj[9];
          float rr = Pm[15] + Pj[15] + 1.0f;
          float w = 1.0f;
          if (dx * dx + dy * dy <= rr * rr) w = pair_weight(Pm, Pj);
          sc[j] *= w;
        }
      }
    }
    __syncthreads();
  }
}

extern "C" void kernel_launch(void* const* d_in, const int* in_sizes, int n_in,
                              void* d_out, int out_size, void* d_ws, size_t ws_size,
                              hipStream_t stream) {
  const float* boxes = (const float*)d_in[0];
  const float* scores = (const float*)d_in[1];
  if (n_in >= 2 && in_sizes[0] == N && in_sizes[1] == 5 * N) {
    boxes = (const float*)d_in[1];
    scores = (const float*)d_in[0];
  }
  float* out = (float*)d_out;
  char* ws = (char*)d_ws;
  float* prep = (float*)ws;

  prep_kernel<<<8, 256, 0, stream>>>(boxes, prep);
  if (ws_size >= DENSE_NEED) {
    float* W = (float*)(ws + W_OFF);
    inter_kernel<<<16384, 256, 0, stream>>>(prep, W);
    scan_dense<<<1, 1024, 0, stream>>>(W, scores, out);
  } else {
    scan_fly<<<1, 1024, 0, stream>>>(prep, scores, out);
  }
}

// Round 9
// 3752.869 us; speedup vs baseline: 1.6656x; 1.6656x over previous
//
#include <hip/hip_runtime.h>
#include <math.h>

#define N 2048
#define CAP (1u << 20)

typedef unsigned int uint;
typedef unsigned long long ull;

// ws layout (big): [0] counter | [256] prep 128KB | [131328] pairs 4MB | [4325632] W 16MB
#define PREP_OFF  256
#define PAIRS_OFF (PREP_OFF + 131072)
#define W_OFF_BIG (PAIRS_OFF + (size_t)CAP * 4)
#define NEED_BIG  (W_OFF_BIG + 16777216ull)
// small layout: W right after prep (no compaction)
#define W_OFF_SMALL PAIRS_OFF
#define NEED_SMALL  (W_OFF_SMALL + 16777216ull)

__global__ void zero_kernel(uint* __restrict__ counter) { *counter = 0u; }

// Per-box precompute: corners (4x2), center, cos/sin, half-extents, area, bounding radius.
__global__ __launch_bounds__(256) void prep_kernel(const float* __restrict__ boxes, float* __restrict__ prep) {
#pragma clang fp contract(off)
  int i = blockIdx.x * 256 + threadIdx.x;
  if (i >= N) return;
  float xc = boxes[i * 5 + 0], yc = boxes[i * 5 + 1];
  float w = boxes[i * 5 + 2], h = boxes[i * 5 + 3], th = boxes[i * 5 + 4];
  float t = th * 0.017453292519943295f;
  float c = (float)cos((double)t);
  float s = (float)sin((double)t);
  float w2 = w * 0.5f, h2 = h * 0.5f;
  float lx[4] = {-w2, w2, w2, -w2};
  float ly[4] = {-h2, -h2, h2, h2};
  float* P = prep + i * 16;
#pragma unroll
  for (int k = 0; k < 4; k++) {
    P[k * 2 + 0] = (xc + lx[k] * c) - ly[k] * s;
    P[k * 2 + 1] = (yc + lx[k] * s) + ly[k] * c;
  }
  P[8] = xc; P[9] = yc; P[10] = c; P[11] = s; P[12] = w2; P[13] = h2;
  P[14] = w * h;
  P[15] = sqrtf(w2 * w2 + h2 * h2);
}

__global__ __launch_bounds__(256) void winit_kernel(float4* __restrict__ W4) {
  uint gid = blockIdx.x * 256u + threadIdx.x;
  W4[gid] = make_float4(1.f, 1.f, 1.f, 1.f);
}

// Bounding-circle filter + ballot-compacted pair list. Disjoint circles => inter == 0
// exactly => w == 1 (already in W), bit-exact vs reference.
__global__ __launch_bounds__(256) void pairs_kernel(const float* __restrict__ prep,
                                                    uint* __restrict__ pairs,
                                                    uint* __restrict__ counter) {
  uint gid = blockIdx.x * 256u + threadIdx.x;
  uint i = gid >> 11, j = gid & 2047u;
  const float* Pi = prep + i * 16;
  const float* Pj = prep + j * 16;
  float dx = Pi[8] - Pj[8], dy = Pi[9] - Pj[9];
  float rr = Pi[15] + Pj[15] + 1.0f;
  bool keep = (dx * dx + dy * dy) <= rr * rr;
  ull m = __ballot(keep);
  if (m == 0ull) return;
  int lane = (int)(threadIdx.x & 63u);
  int leader = __ffsll((long long)m) - 1;
  uint base = 0;
  if (lane == leader) base = atomicAdd(counter, (uint)__popcll(m));
  base = (uint)__shfl((int)base, leader);
  if (keep) {
    uint pos = base + (uint)__popcll(m & ((1ull << lane) - 1ull));
    if (pos < CAP) pairs[pos] = (i << 11) | j;
  }
}

// Rotated-rect intersection weight, mirroring the reference op-for-op in fp32.
// Sort is a fully-unrolled STABLE bitonic-32 on (ang, idx): static indexing ->
// registers (no scratch spill), lexicographic key == stable argsort result.
__device__ float pair_weight(const float* __restrict__ Pi, const float* __restrict__ Pj) {
#pragma clang fp contract(off)
  float ax[4], ay[4], bx[4], by[4];
#pragma unroll
  for (int k = 0; k < 4; k++) {
    ax[k] = Pi[2 * k]; ay[k] = Pi[2 * k + 1];
    bx[k] = Pj[2 * k]; by[k] = Pj[2 * k + 1];
  }
  float ptsx[24], ptsy[24];
  bool msk[24];
#pragma unroll
  for (int e = 0; e < 4; e++) {
    float Ax = ax[e], Ay = ay[e];
    float BAx = ax[(e + 1) & 3] - Ax, BAy = ay[(e + 1) & 3] - Ay;
#pragma unroll
    for (int f = 0; f < 4; f++) {
      float Cx = bx[f], Cy = by[f];
      float DCx = bx[(f + 1) & 3] - Cx, DCy = by[(f + 1) & 3] - Cy;
      float CAx = Cx - Ax, CAy = Cy - Ay;
      float den = BAx * DCy - BAy * DCx;
      bool dok = fabsf(den) > 1e-12f;
      float dens = dok ? den : 1.0f;
      float t = (CAx * DCy - CAy * DCx) / dens;
      float u = (CAx * BAy - CAy * BAx) / dens;
      int id = e * 4 + f;
      ptsx[id] = Ax + t * BAx;
      ptsy[id] = Ay + t * BAy;
      msk[id] = dok && (t >= 0.0f) && (t <= 1.0f) && (u >= 0.0f) && (u <= 1.0f);
    }
  }
  float xcj = Pj[8], ycj = Pj[9], cj = Pj[10], sj = Pj[11], w2j = Pj[12], h2j = Pj[13];
  float xci = Pi[8], yci = Pi[9], ci = Pi[10], si = Pi[11], w2i = Pi[12], h2i = Pi[13];
#pragma unroll
  for (int k = 0; k < 4; k++) {
    float dx = ax[k] - xcj, dy = ay[k] - ycj;
    float xl = dx * cj + dy * sj;
    float yl = -dx * sj + dy * cj;
    ptsx[16 + k] = ax[k]; ptsy[16 + k] = ay[k];
    msk[16 + k] = (fabsf(xl) <= w2j + 1e-5f) && (fabsf(yl) <= h2j + 1e-5f);
  }
#pragma unroll
  for (int k = 0; k < 4; k++) {
    float dx = bx[k] - xci, dy = by[k] - yci;
    float xl = dx * ci + dy * si;
    float yl = -dx * si + dy * ci;
    ptsx[20 + k] = bx[k]; ptsy[20 + k] = by[k];
    msk[20 + k] = (fabsf(xl) <= w2i + 1e-5f) && (fabsf(yl) <= h2i + 1e-5f);
  }
  int cnt = 0;
  float sx = 0.f, sy = 0.f;
#pragma unroll
  for (int k = 0; k < 24; k++) {
    if (msk[k]) { cnt++; sx += ptsx[k]; sy += ptsy[k]; }
  }
  float fc = (float)(cnt > 1 ? cnt : 1);
  float ctx = sx / fc, cty = sy / fc;
  float ang[32], px[32], py[32];
  int idp[32];
#pragma unroll
  for (int k = 0; k < 24; k++) {
    float rx = ptsx[k] - ctx, ry = ptsy[k] - cty;
    px[k] = rx; py[k] = ry; idp[k] = k;
    ang[k] = msk[k] ? (float)atan2((double)ry, (double)rx) : 1.0e3f;
  }
#pragma unroll
  for (int k = 24; k < 32; k++) { ang[k] = 1.0e30f; px[k] = 0.f; py[k] = 0.f; idp[k] = k; }
#pragma unroll
  for (int k = 2; k <= 32; k <<= 1) {
#pragma unroll
    for (int j = k >> 1; j > 0; j >>= 1) {
#pragma unroll
      for (int x = 0; x < 32; x++) {
        int l = x ^ j;
        if (l > x) {
          bool up = ((x & k) == 0);
          bool gt = (ang[x] > ang[l]) || (ang[x] == ang[l] && idp[x] > idp[l]);
          if (gt == up) {
            float t0 = ang[x]; ang[x] = ang[l]; ang[l] = t0;
            float t1 = px[x]; px[x] = px[l]; px[l] = t1;
            float t2 = py[x]; py[x] = py[l]; py[l] = t2;
            int t3 = idp[x]; idp[x] = idp[l]; idp[l] = t3;
          }
        }
      }
    }
  }
  float term[24];
#pragma unroll
  for (int x = 0; x < 24; x++) {
    int nx = (x + 1 < cnt) ? x + 1 : 0;
    float cr = px[x] * py[nx] - py[x] * px[nx];
    term[x] = (x < cnt) ? cr : 0.0f;
  }
  // numpy pairwise summation order for n=24
  float r[8];
#pragma unroll
  for (int j = 0; j < 8; j++) r[j] = (term[j] + term[j + 8]) + term[j + 16];
  float ssum = ((r[0] + r[1]) + (r[2] + r[3])) + ((r[4] + r[5]) + (r[6] + r[7]));
  float area = 0.5f * fabsf(ssum);
  float inter = (cnt >= 3) ? area : 0.0f;
  float iou = inter / ((Pi[14] + Pj[14] - inter) + 1e-9f);
  return (iou > 0.3f) ? (1.0f - iou) : 1.0f;  // METHOD=1 linear decay
}

// Heavy geometry only on compacted surviving pairs.
__global__ __launch_bounds__(64, 2) void interB_kernel(const float* __restrict__ prep,
                                                       const uint* __restrict__ pairs,
                                                       const uint* __restrict__ counter,
                                                       float* __restrict__ W) {
  uint idx = blockIdx.x * 64u + threadIdx.x;
  uint n = *counter;
  if (n > CAP) n = CAP;
  if (idx >= n) return;
  uint pk = pairs[idx];
  uint i = pk >> 11, j = pk & 2047u;
  W[(size_t)i * N + j] = pair_weight(prep + i * 16, prep + j * 16);
}

// Dense fallback (no pair-list space): one thread per pair.
__global__ __launch_bounds__(64, 2) void inter_dense(const float* __restrict__ prep,
                                                     float* __restrict__ W) {
  uint gid = blockIdx.x * 64u + threadIdx.x;
  uint i = gid >> 11, j = gid & 2047u;
  const float* Pi = prep + i * 16;
  const float* Pj = prep + j * 16;
  float dx = Pi[8] - Pj[8], dy = Pi[9] - Pj[9];
  float rr = Pi[15] + Pj[15] + 1.0f;
  float w = 1.0f;
  if (dx * dx + dy * dy <= rr * rr) w = pair_weight(Pi, Pj);
  W[(size_t)i * N + j] = w;
}

// Sequential soft-NMS scan: ONE wave, zero barriers. Lane owns 32 scores in
// registers (j = 4*lane + 256*k + c), selected = 32-bit mask. Argmax = register
// fmaxf tree + min-index-among-equals (np.argmax first-index semantics), then
// 6-level shfl_xor butterfly. Decay = 8 coalesced dwordx4 loads of W row.
// Multiplying selected slots is safe: their values are never read again.
__global__ __launch_bounds__(64) void scan_wave(const float* __restrict__ W,
                                                const float* __restrict__ scores,
                                                float* __restrict__ out) {
#pragma clang fp contract(off)
  int lane = threadIdx.x;
  const float4* sc4 = (const float4*)scores;
  float s[32];
#pragma unroll
  for (int k = 0; k < 8; k++) {
    float4 v = sc4[lane + 64 * k];
    s[4 * k + 0] = v.x; s[4 * k + 1] = v.y; s[4 * k + 2] = v.z; s[4 * k + 3] = v.w;
  }
  uint selmask = 0u;
  const float NINF = -__builtin_inff();
  const int jbase = 4 * lane;
  for (int t = 0; t < N; ++t) {
    float m[32];
#pragma unroll
    for (int g = 0; g < 32; g++) m[g] = ((selmask >> g) & 1u) ? NINF : s[g];
    // max tree
    float a16[16], a8[8], a4[4], a2[2];
#pragma unroll
    for (int g = 0; g < 16; g++) a16[g] = fmaxf(m[g], m[g + 16]);
#pragma unroll
    for (int g = 0; g < 8; g++) a8[g] = fmaxf(a16[g], a16[g + 8]);
#pragma unroll
    for (int g = 0; g < 4; g++) a4[g] = fmaxf(a8[g], a8[g + 4]);
    a2[0] = fmaxf(a4[0], a4[2]); a2[1] = fmaxf(a4[1], a4[3]);
    float mv = fmaxf(a2[0], a2[1]);
    // min index among equals (j = 256*(g>>2) + (g&3) + 4*lane, ascending in g)
    int j32[32];
#pragma unroll
    for (int g = 0; g < 32; g++) {
      int j = ((g >> 2) << 8) + (g & 3) + jbase;
      j32[g] = (m[g] == mv) ? j : 0x7FFFFFFF;
    }
    int b16[16], b8[8], b4[4];
#pragma unroll
    for (int g = 0; g < 16; g++) b16[g] = min(j32[g], j32[g + 16]);
#pragma unroll
    for (int g = 0; g < 8; g++) b8[g] = min(b16[g], b16[g + 8]);
#pragma unroll
    for (int g = 0; g < 4; g++) b4[g] = min(b8[g], b8[g + 4]);
    int bj = min(min(b4[0], b4[1]), min(b4[2], b4[3]));
    // wave butterfly: global (mv, bj) with first-index tie-break
#pragma unroll
    for (int off = 32; off > 0; off >>= 1) {
      float ov = __shfl_xor(mv, off);
      int oj = __shfl_xor(bj, off);
      if (ov > mv || (ov == mv && oj < bj)) { mv = ov; bj = oj; }
    }
    if (lane == 0) {
      out[t] = (float)bj;
      out[N + t] = (mv > 0.001f) ? 1.0f : 0.0f;
      out[2 * N + t] = mv;
    }
    if (((bj >> 2) & 63) == lane) selmask |= 1u << (((bj >> 8) << 2) | (bj & 3));
    if (mv > 0.001f) {
      const float4* Wr = (const float4*)(W + (size_t)bj * N);
#pragma unroll
      for (int k = 0; k < 8; k++) {
        float4 w = Wr[lane + 64 * k];
        s[4 * k + 0] *= w.x; s[4 * k + 1] *= w.y; s[4 * k + 2] *= w.z; s[4 * k + 3] *= w.w;
      }
    }
  }
}

// Ultra-small-ws fallback: recompute selected row on the fly (never expected).
__global__ __launch_bounds__(1024) void scan_fly(const float* __restrict__ prep,
                                                 const float* __restrict__ scores,
                                                 float* __restrict__ out) {
  __shared__ float sc[N];
  __shared__ unsigned char sel[N];
  __shared__ float rv[16];
  __shared__ int ri[16];
  int tid = threadIdx.x;
  sc[tid] = scores[tid];
  sc[tid + 1024] = scores[tid + 1024];
  sel[tid] = 0;
  sel[tid + 1024] = 0;
  __syncthreads();
  const float NINF = -__builtin_inff();
  for (int t = 0; t < N; ++t) {
    float v0 = sel[tid] ? NINF : sc[tid];
    float v1 = sel[tid + 1024] ? NINF : sc[tid + 1024];
    float bv; int bi;
    if (v0 >= v1) { bv = v0; bi = tid; } else { bv = v1; bi = tid + 1024; }
#pragma unroll
    for (int off = 32; off > 0; off >>= 1) {
      float ov = __shfl_down(bv, off);
      int oi = __shfl_down(bi, off);
      if (ov > bv || (ov == bv && oi < bi)) { bv = ov; bi = oi; }
    }
    if ((tid & 63) == 0) { rv[tid >> 6] = bv; ri[tid >> 6] = bi; }
    __syncthreads();
    float mv = rv[0]; int mi = ri[0];
#pragma unroll
    for (int k = 1; k < 16; k++) {
      float ov = rv[k]; int oi = ri[k];
      if (ov > mv || (ov == mv && oi < mi)) { mv = ov; mi = oi; }
    }
    if (tid == 0) {
      out[t] = (float)mi;
      out[N + t] = (mv > 0.001f) ? 1.0f : 0.0f;
      out[2 * N + t] = mv;
    }
    if (tid == (mi & 1023)) sel[mi] = 1;
    if (mv > 0.001f) {
      const float* Pm = prep + mi * 16;
#pragma unroll
      for (int half = 0; half < 2; half++) {
        int j = tid + half * 1024;
        if (!sel[j]) {
          const float* Pj = prep + j * 16;
          float dx = Pm[8] - Pj[8], dy = Pm[9] - Pj[9];
          float rr = Pm[15] + Pj[15] + 1.0f;
          float w = 1.0f;
          if (dx * dx + dy * dy <= rr * rr) w = pair_weight(Pm, Pj);
          sc[j] *= w;
        }
      }
    }
    __syncthreads();
  }
}

extern "C" void kernel_launch(void* const* d_in, const int* in_sizes, int n_in,
                              void* d_out, int out_size, void* d_ws, size_t ws_size,
                              hipStream_t stream) {
  const float* boxes = (const float*)d_in[0];
  const float* scores = (const float*)d_in[1];
  if (n_in >= 2 && in_sizes[0] == N && in_sizes[1] == 5 * N) {
    boxes = (const float*)d_in[1];
    scores = (const float*)d_in[0];
  }
  float* out = (float*)d_out;
  char* ws = (char*)d_ws;
  uint* counter = (uint*)ws;
  float* prep = (float*)(ws + PREP_OFF);

  prep_kernel<<<8, 256, 0, stream>>>(boxes, prep);
  if (ws_size >= NEED_BIG) {
    uint* pairs = (uint*)(ws + PAIRS_OFF);
    float* W = (float*)(ws + W_OFF_BIG);
    zero_kernel<<<1, 1, 0, stream>>>(counter);
    winit_kernel<<<4096, 256, 0, stream>>>((float4*)W);
    pairs_kernel<<<16384, 256, 0, stream>>>(prep, pairs, counter);
    interB_kernel<<<CAP / 64, 64, 0, stream>>>(prep, pairs, counter, W);
    scan_wave<<<1, 64, 0, stream>>>(W, scores, out);
  } else if (ws_size >= NEED_SMALL) {
    float* W = (float*)(ws + W_OFF_SMALL);
    inter_dense<<<65536, 64, 0, stream>>>(prep, W);
    scan_wave<<<1, 64, 0, stream>>>(W, scores, out);
  } else {
    scan_fly<<<1, 1024, 0, stream>>>(prep, scores, out);
  }
}

// Round 10
// 3388.536 us; speedup vs baseline: 1.8447x; 1.1075x over previous
//
#include <hip/hip_runtime.h>
#include <math.h>

#define N 2048
#define CAP (1u << 20)

typedef unsigned int uint;
typedef unsigned long long ull;

// ws layout (big): [0] counter | [256] prep 128KB | [131328] pairs 4MB | [4325632] W 16MB
#define PREP_OFF  256
#define PAIRS_OFF (PREP_OFF + 131072)
#define W_OFF_BIG (PAIRS_OFF + (size_t)CAP * 4)
#define NEED_BIG  (W_OFF_BIG + 16777216ull)
#define W_OFF_SMALL PAIRS_OFF
#define NEED_SMALL  (W_OFF_SMALL + 16777216ull)

// ---------- DPP wave-64 reductions (VALU latency, no LDS) ----------
// row_shr:1/2/4/8 then row_bcast:15 (0x142), row_bcast:31 (0x143); result lane 63.
__device__ __forceinline__ float wave_max_f32_bcast(float v) {
  int x = __float_as_int(v);
  const int ID = 0xFF800000;  // -inf
  int t;
  t = __builtin_amdgcn_update_dpp(ID, x, 0x111, 0xF, 0xF, false);
  x = __float_as_int(fmaxf(__int_as_float(x), __int_as_float(t)));
  t = __builtin_amdgcn_update_dpp(ID, x, 0x112, 0xF, 0xF, false);
  x = __float_as_int(fmaxf(__int_as_float(x), __int_as_float(t)));
  t = __builtin_amdgcn_update_dpp(ID, x, 0x114, 0xF, 0xF, false);
  x = __float_as_int(fmaxf(__int_as_float(x), __int_as_float(t)));
  t = __builtin_amdgcn_update_dpp(ID, x, 0x118, 0xF, 0xF, false);
  x = __float_as_int(fmaxf(__int_as_float(x), __int_as_float(t)));
  t = __builtin_amdgcn_update_dpp(ID, x, 0x142, 0xF, 0xF, false);
  x = __float_as_int(fmaxf(__int_as_float(x), __int_as_float(t)));
  t = __builtin_amdgcn_update_dpp(ID, x, 0x143, 0xF, 0xF, false);
  x = __float_as_int(fmaxf(__int_as_float(x), __int_as_float(t)));
  x = __builtin_amdgcn_readlane(x, 63);
  return __int_as_float(x);
}
__device__ __forceinline__ int wave_min_i32_bcast(int v) {
  const int ID = 0x7FFFFFFF;  // values are >= 0
  int t;
  t = __builtin_amdgcn_update_dpp(ID, v, 0x111, 0xF, 0xF, false); v = min(v, t);
  t = __builtin_amdgcn_update_dpp(ID, v, 0x112, 0xF, 0xF, false); v = min(v, t);
  t = __builtin_amdgcn_update_dpp(ID, v, 0x114, 0xF, 0xF, false); v = min(v, t);
  t = __builtin_amdgcn_update_dpp(ID, v, 0x118, 0xF, 0xF, false); v = min(v, t);
  t = __builtin_amdgcn_update_dpp(ID, v, 0x142, 0xF, 0xF, false); v = min(v, t);
  t = __builtin_amdgcn_update_dpp(ID, v, 0x143, 0xF, 0xF, false); v = min(v, t);
  return __builtin_amdgcn_readlane(v, 63);
}

// Per-box precompute (+ counter zero folded in).
__global__ __launch_bounds__(256) void prep_kernel(const float* __restrict__ boxes,
                                                   float* __restrict__ prep,
                                                   uint* __restrict__ counter) {
#pragma clang fp contract(off)
  int i = blockIdx.x * 256 + threadIdx.x;
  if (i == 0) *counter = 0u;
  if (i >= N) return;
  float xc = boxes[i * 5 + 0], yc = boxes[i * 5 + 1];
  float w = boxes[i * 5 + 2], h = boxes[i * 5 + 3], th = boxes[i * 5 + 4];
  float t = th * 0.017453292519943295f;
  float c = (float)cos((double)t);
  float s = (float)sin((double)t);
  float w2 = w * 0.5f, h2 = h * 0.5f;
  float lx[4] = {-w2, w2, w2, -w2};
  float ly[4] = {-h2, -h2, h2, h2};
  float* P = prep + i * 16;
#pragma unroll
  for (int k = 0; k < 4; k++) {
    P[k * 2 + 0] = (xc + lx[k] * c) - ly[k] * s;
    P[k * 2 + 1] = (yc + lx[k] * s) + ly[k] * c;
  }
  P[8] = xc; P[9] = yc; P[10] = c; P[11] = s; P[12] = w2; P[13] = h2;
  P[14] = w * h;
  P[15] = sqrtf(w2 * w2 + h2 * h2);
}

// Bounding-circle filter: rejected pairs write W=1.0 inline (winit fused away);
// survivors go to the compacted list for the heavy kernel.
__global__ __launch_bounds__(256) void pairs_kernel(const float* __restrict__ prep,
                                                    uint* __restrict__ pairs,
                                                    uint* __restrict__ counter,
                                                    float* __restrict__ W) {
  uint gid = blockIdx.x * 256u + threadIdx.x;
  uint i = gid >> 11, j = gid & 2047u;
  const float* Pi = prep + i * 16;
  const float* Pj = prep + j * 16;
  float dx = Pi[8] - Pj[8], dy = Pi[9] - Pj[9];
  float rr = Pi[15] + Pj[15] + 1.0f;
  bool keep = (dx * dx + dy * dy) <= rr * rr;
  if (!keep) W[(size_t)i * N + j] = 1.0f;  // disjoint circles => inter==0 => w==1 exact
  ull m = __ballot(keep);
  if (m == 0ull) return;
  int lane = (int)(threadIdx.x & 63u);
  int leader = __ffsll((long long)m) - 1;
  uint base = 0;
  if (lane == leader) base = atomicAdd(counter, (uint)__popcll(m));
  base = (uint)__shfl((int)base, leader);
  if (keep) {
    uint pos = base + (uint)__popcll(m & ((1ull << lane) - 1ull));
    if (pos < CAP) pairs[pos] = (i << 11) | j;
    else W[(size_t)i * N + j] = 1.0f;  // overflow guard (never taken for this input)
  }
}

// Rotated-rect intersection weight, mirroring the reference op-for-op in fp32.
__device__ float pair_weight(const float* __restrict__ Pi, const float* __restrict__ Pj) {
#pragma clang fp contract(off)
  float ax[4], ay[4], bx[4], by[4];
#pragma unroll
  for (int k = 0; k < 4; k++) {
    ax[k] = Pi[2 * k]; ay[k] = Pi[2 * k + 1];
    bx[k] = Pj[2 * k]; by[k] = Pj[2 * k + 1];
  }
  float ptsx[24], ptsy[24];
  bool msk[24];
#pragma unroll
  for (int e = 0; e < 4; e++) {
    float Ax = ax[e], Ay = ay[e];
    float BAx = ax[(e + 1) & 3] - Ax, BAy = ay[(e + 1) & 3] - Ay;
#pragma unroll
    for (int f = 0; f < 4; f++) {
      float Cx = bx[f], Cy = by[f];
      float DCx = bx[(f + 1) & 3] - Cx, DCy = by[(f + 1) & 3] - Cy;
      float CAx = Cx - Ax, CAy = Cy - Ay;
      float den = BAx * DCy - BAy * DCx;
      bool dok = fabsf(den) > 1e-12f;
      float dens = dok ? den : 1.0f;
      float t = (CAx * DCy - CAy * DCx) / dens;
      float u = (CAx * BAy - CAy * BAx) / dens;
      int id = e * 4 + f;
      ptsx[id] = Ax + t * BAx;
      ptsy[id] = Ay + t * BAy;
      msk[id] = dok && (t >= 0.0f) && (t <= 1.0f) && (u >= 0.0f) && (u <= 1.0f);
    }
  }
  float xcj = Pj[8], ycj = Pj[9], cj = Pj[10], sj = Pj[11], w2j = Pj[12], h2j = Pj[13];
  float xci = Pi[8], yci = Pi[9], ci = Pi[10], si = Pi[11], w2i = Pi[12], h2i = Pi[13];
#pragma unroll
  for (int k = 0; k < 4; k++) {
    float dx = ax[k] - xcj, dy = ay[k] - ycj;
    float xl = dx * cj + dy * sj;
    float yl = -dx * sj + dy * cj;
    ptsx[16 + k] = ax[k]; ptsy[16 + k] = ay[k];
    msk[16 + k] = (fabsf(xl) <= w2j + 1e-5f) && (fabsf(yl) <= h2j + 1e-5f);
  }
#pragma unroll
  for (int k = 0; k < 4; k++) {
    float dx = bx[k] - xci, dy = by[k] - yci;
    float xl = dx * ci + dy * si;
    float yl = -dx * si + dy * ci;
    ptsx[20 + k] = bx[k]; ptsy[20 + k] = by[k];
    msk[20 + k] = (fabsf(xl) <= w2i + 1e-5f) && (fabsf(yl) <= h2i + 1e-5f);
  }
  int cnt = 0;
  float sx = 0.f, sy = 0.f;
#pragma unroll
  for (int k = 0; k < 24; k++) {
    if (msk[k]) { cnt++; sx += ptsx[k]; sy += ptsy[k]; }
  }
  float fc = (float)(cnt > 1 ? cnt : 1);
  float ctx = sx / fc, cty = sy / fc;
  float ang[32], px[32], py[32];
  int idp[32];
#pragma unroll
  for (int k = 0; k < 24; k++) {
    float rx = ptsx[k] - ctx, ry = ptsy[k] - cty;
    px[k] = rx; py[k] = ry; idp[k] = k;
    ang[k] = msk[k] ? (float)atan2((double)ry, (double)rx) : 1.0e3f;
  }
#pragma unroll
  for (int k = 24; k < 32; k++) { ang[k] = 1.0e30f; px[k] = 0.f; py[k] = 0.f; idp[k] = k; }
#pragma unroll
  for (int k = 2; k <= 32; k <<= 1) {
#pragma unroll
    for (int j = k >> 1; j > 0; j >>= 1) {
#pragma unroll
      for (int x = 0; x < 32; x++) {
        int l = x ^ j;
        if (l > x) {
          bool up = ((x & k) == 0);
          bool gt = (ang[x] > ang[l]) || (ang[x] == ang[l] && idp[x] > idp[l]);
          if (gt == up) {
            float t0 = ang[x]; ang[x] = ang[l]; ang[l] = t0;
            float t1 = px[x]; px[x] = px[l]; px[l] = t1;
            float t2 = py[x]; py[x] = py[l]; py[l] = t2;
            int t3 = idp[x]; idp[x] = idp[l]; idp[l] = t3;
          }
        }
      }
    }
  }
  float term[24];
#pragma unroll
  for (int x = 0; x < 24; x++) {
    int nx = (x + 1 < cnt) ? x + 1 : 0;
    float cr = px[x] * py[nx] - py[x] * px[nx];
    term[x] = (x < cnt) ? cr : 0.0f;
  }
  float r[8];
#pragma unroll
  for (int j = 0; j < 8; j++) r[j] = (term[j] + term[j + 8]) + term[j + 16];
  float ssum = ((r[0] + r[1]) + (r[2] + r[3])) + ((r[4] + r[5]) + (r[6] + r[7]));
  float area = 0.5f * fabsf(ssum);
  float inter = (cnt >= 3) ? area : 0.0f;
  float iou = inter / ((Pi[14] + Pj[14] - inter) + 1e-9f);
  return (iou > 0.3f) ? (1.0f - iou) : 1.0f;
}

__global__ __launch_bounds__(64, 2) void interB_kernel(const float* __restrict__ prep,
                                                       const uint* __restrict__ pairs,
                                                       const uint* __restrict__ counter,
                                                       float* __restrict__ W) {
  uint idx = blockIdx.x * 64u + threadIdx.x;
  uint n = *counter;
  if (n > CAP) n = CAP;
  if (idx >= n) return;
  uint pk = pairs[idx];
  uint i = pk >> 11, j = pk & 2047u;
  W[(size_t)i * N + j] = pair_weight(prep + i * 16, prep + j * 16);
}

__global__ __launch_bounds__(64, 2) void inter_dense(const float* __restrict__ prep,
                                                     float* __restrict__ W) {
  uint gid = blockIdx.x * 64u + threadIdx.x;
  uint i = gid >> 11, j = gid & 2047u;
  const float* Pi = prep + i * 16;
  const float* Pj = prep + j * 16;
  float dx = Pi[8] - Pj[8], dy = Pi[9] - Pj[9];
  float rr = Pi[15] + Pj[15] + 1.0f;
  float w = 1.0f;
  if (dx * dx + dy * dy <= rr * rr) w = pair_weight(Pi, Pj);
  W[(size_t)i * N + j] = w;
}

#define OFFG(g) ((((g) >> 2) << 8) + ((g) & 3))

// Sequential soft-NMS scan, one wave. DPP argmax; runner-up row prefetch in
// registers; once max <= thresh the rest is a bitonic sort of remaining keys
// (scores never increase => no more decay => selection == sort).
__global__ __launch_bounds__(64, 1) void scan_wave(const float* __restrict__ W,
                                                   const float* __restrict__ scores,
                                                   float* __restrict__ out) {
#pragma clang fp contract(off)
  __shared__ ull keys[N];
  const int lane = threadIdx.x;
  const int jbase = 4 * lane;
  const float4* sc4 = (const float4*)scores;
  float s[32], fm[32];
#pragma unroll
  for (int k = 0; k < 8; k++) {
    float4 v = sc4[lane + 64 * k];
    s[4 * k + 0] = v.x; s[4 * k + 1] = v.y; s[4 * k + 2] = v.z; s[4 * k + 3] = v.w;
    fm[4 * k + 0] = 0.f; fm[4 * k + 1] = 0.f; fm[4 * k + 2] = 0.f; fm[4 * k + 3] = 0.f;
  }
  const int BIG = 0x7FFFFFFF;
  int pred = -1;
  float4 pf[8];
#pragma unroll
  for (int k = 0; k < 8; k++) pf[k] = make_float4(0.f, 0.f, 0.f, 0.f);
  int t = 0;
  for (; t < N; ++t) {
    // masked view: selected elements pushed to [-4,-3] (never equal to any avail >= 0)
    float m[32];
#pragma unroll
    for (int g = 0; g < 32; g++) m[g] = fmaf(fm[g], -4.0f, s[g]);
    // local max tree
    float a16[16], a8[8], a4[4];
#pragma unroll
    for (int g = 0; g < 16; g++) a16[g] = fmaxf(m[g], m[g + 16]);
#pragma unroll
    for (int g = 0; g < 8; g++) a8[g] = fmaxf(a16[g], a16[g + 8]);
#pragma unroll
    for (int g = 0; g < 4; g++) a4[g] = fmaxf(a8[g], a8[g + 4]);
    float lmv = fmaxf(fmaxf(a4[0], a4[1]), fmaxf(a4[2], a4[3]));
    float gmax = wave_max_f32_bcast(lmv);
    if (!(gmax > 0.001f)) break;  // tail phase: no more decay ever
    // local min element-offset among m[g] == gmax
    int c[32];
#pragma unroll
    for (int g = 0; g < 32; g++) c[g] = (m[g] == gmax) ? OFFG(g) : BIG;
    int b16[16], b8[8], b4[4];
#pragma unroll
    for (int g = 0; g < 16; g++) b16[g] = min(c[g], c[g + 16]);
#pragma unroll
    for (int g = 0; g < 8; g++) b8[g] = min(b16[g], b16[g + 8]);
#pragma unroll
    for (int g = 0; g < 4; g++) b4[g] = min(b8[g], b8[g + 4]);
    int lmin = min(min(b4[0], b4[1]), min(b4[2], b4[3]));
    int cand = (lmin == BIG) ? BIG : (lmin + jbase);
    int bj = wave_min_i32_bcast(cand);
    if (lane == 0) {
      out[t] = (float)bj;
      out[N + t] = 1.0f;
      out[2 * N + t] = gmax;
    }
    // mark selected
    int d = bj - jbase;
#pragma unroll
    for (int g = 0; g < 32; g++) if (OFFG(g) == d) fm[g] = 1.0f;
    // fetch decay row: register-prefetched if predicted correctly
    float4 w[8];
    if (bj == pred) {
#pragma unroll
      for (int k = 0; k < 8; k++) w[k] = pf[k];
    } else {
      const float4* Wr = (const float4*)(W + (size_t)bj * N);
#pragma unroll
      for (int k = 0; k < 8; k++) w[k] = Wr[lane + 64 * k];
    }
    // predict next pick = runner-up excluding the owner lane (cheap, lossy is fine)
    int ownerlane = (bj >> 2) & 63;
    float cp = (lane == ownerlane) ? -__builtin_inff() : lmv;
    float g2 = wave_max_f32_bcast(cp);
    int c2[32];
#pragma unroll
    for (int g = 0; g < 32; g++) c2[g] = (m[g] == g2 && lane != ownerlane) ? OFFG(g) : BIG;
#pragma unroll
    for (int g = 0; g < 16; g++) b16[g] = min(c2[g], c2[g + 16]);
#pragma unroll
    for (int g = 0; g < 8; g++) b8[g] = min(b16[g], b16[g + 8]);
#pragma unroll
    for (int g = 0; g < 4; g++) b4[g] = min(b8[g], b8[g + 4]);
    int lmin2 = min(min(b4[0], b4[1]), min(b4[2], b4[3]));
    int cand2 = (lmin2 == BIG) ? BIG : (lmin2 + jbase);
    int pj = wave_min_i32_bcast(cand2);
    pred = pj;
    if (pj < N) {  // speculative row load into registers (consumed next iter on hit)
      const float4* Wp = (const float4*)(W + (size_t)pj * N);
#pragma unroll
      for (int k = 0; k < 8; k++) pf[k] = Wp[lane + 64 * k];
    }
    // decay (selected slots multiplied too: their values are never used again)
#pragma unroll
    for (int k = 0; k < 8; k++) {
      s[4 * k + 0] *= w[k].x; s[4 * k + 1] *= w[k].y;
      s[4 * k + 2] *= w[k].z; s[4 * k + 3] *= w[k].w;
    }
  }
  if (t < N) {
    // Tail: remaining selection order == sort avail by (score desc, index asc).
    // key = ((score_bits<<32) | (2047-j)) + 1 for avail (score>=0 so bits are
    // monotonic); 0 for selected. +1 can't carry (lo <= 2047).
#pragma unroll
    for (int g = 0; g < 32; g++) {
      int j = jbase + OFFG(g);
      ull key = (fm[g] == 0.0f)
                    ? ((((ull)(uint)__float_as_int(s[g])) << 32) | (ull)(uint)(2047 - j)) + 1ull
                    : 0ull;
      keys[j] = key;
    }
    __syncthreads();
    for (int k = 2; k <= N; k <<= 1) {
      for (int jj = k >> 1; jj > 0; jj >>= 1) {
        for (int p = lane; p < N / 2; p += 64) {
          int i1 = ((p & ~(jj - 1)) << 1) | (p & (jj - 1));
          int i2 = i1 | jj;
          ull a = keys[i1], b = keys[i2];
          bool up = ((i1 & k) == 0);
          if (up ? (a < b) : (a > b)) { keys[i1] = b; keys[i2] = a; }
        }
        __syncthreads();
      }
    }
    for (int r = lane; r < N - t; r += 64) {
      ull key = keys[r] - 1ull;
      int j = 2047 - (int)(uint)(key & 0xFFFFFFFFull);
      out[t + r] = (float)j;
      out[N + t + r] = 0.0f;
      out[2 * N + t + r] = __int_as_float((int)(uint)(key >> 32));
    }
  }
}

// Ultra-small-ws fallback (never expected).
__global__ __launch_bounds__(1024) void scan_fly(const float* __restrict__ prep,
                                                 const float* __restrict__ scores,
                                                 float* __restrict__ out) {
  __shared__ float sc[N];
  __shared__ unsigned char sel[N];
  __shared__ float rv[16];
  __shared__ int ri[16];
  int tid = threadIdx.x;
  sc[tid] = scores[tid];
  sc[tid + 1024] = scores[tid + 1024];
  sel[tid] = 0;
  sel[tid + 1024] = 0;
  __syncthreads();
  const float NINF = -__builtin_inff();
  for (int t = 0; t < N; ++t) {
    float v0 = sel[tid] ? NINF : sc[tid];
    float v1 = sel[tid + 1024] ? NINF : sc[tid + 1024];
    float bv; int bi;
    if (v0 >= v1) { bv = v0; bi = tid; } else { bv = v1; bi = tid + 1024; }
#pragma unroll
    for (int off = 32; off > 0; off >>= 1) {
      float ov = __shfl_down(bv, off);
      int oi = __shfl_down(bi, off);
      if (ov > bv || (ov == bv && oi < bi)) { bv = ov; bi = oi; }
    }
    if ((tid & 63) == 0) { rv[tid >> 6] = bv; ri[tid >> 6] = bi; }
    __syncthreads();
    float mv = rv[0]; int mi = ri[0];
#pragma unroll
    for (int k = 1; k < 16; k++) {
      float ov = rv[k]; int oi = ri[k];
      if (ov > mv || (ov == mv && oi < mi)) { mv = ov; mi = oi; }
    }
    if (tid == 0) {
      out[t] = (float)mi;
      out[N + t] = (mv > 0.001f) ? 1.0f : 0.0f;
      out[2 * N + t] = mv;
    }
    if (tid == (mi & 1023)) sel[mi] = 1;
    if (mv > 0.001f) {
      const float* Pm = prep + mi * 16;
#pragma unroll
      for (int half = 0; half < 2; half++) {
        int j = tid + half * 1024;
        if (!sel[j]) {
          const float* Pj = prep + j * 16;
          float dx = Pm[8] - Pj[8], dy = Pm[9] - Pj[9];
          float rr = Pm[15] + Pj[15] + 1.0f;
          float w = 1.0f;
          if (dx * dx + dy * dy <= rr * rr) w = pair_weight(Pm, Pj);
          sc[j] *= w;
        }
      }
    }
    __syncthreads();
  }
}

extern "C" void kernel_launch(void* const* d_in, const int* in_sizes, int n_in,
                              void* d_out, int out_size, void* d_ws, size_t ws_size,
                              hipStream_t stream) {
  const float* boxes = (const float*)d_in[0];
  const float* scores = (const float*)d_in[1];
  if (n_in >= 2 && in_sizes[0] == N && in_sizes[1] == 5 * N) {
    boxes = (const float*)d_in[1];
    scores = (const float*)d_in[0];
  }
  float* out = (float*)d_out;
  char* ws = (char*)d_ws;
  uint* counter = (uint*)ws;
  float* prep = (float*)(ws + PREP_OFF);

  if (ws_size >= NEED_BIG) {
    uint* pairs = (uint*)(ws + PAIRS_OFF);
    float* W = (float*)(ws + W_OFF_BIG);
    prep_kernel<<<8, 256, 0, stream>>>(boxes, prep, counter);
    pairs_kernel<<<16384, 256, 0, stream>>>(prep, pairs, counter, W);
    interB_kernel<<<CAP / 64, 64, 0, stream>>>(prep, pairs, counter, W);
    scan_wave<<<1, 64, 0, stream>>>(W, scores, out);
  } else if (ws_size >= NEED_SMALL) {
    float* W = (float*)(ws + W_OFF_SMALL);
    prep_kernel<<<8, 256, 0, stream>>>(boxes, prep, counter);
    inter_dense<<<65536, 64, 0, stream>>>(prep, W);
    scan_wave<<<1, 64, 0, stream>>>(W, scores, out);
  } else {
    prep_kernel<<<8, 256, 0, stream>>>(boxes, prep, counter);
    scan_fly<<<1, 1024, 0, stream>>>(prep, scores, out);
  }
}